// Round 1
// baseline (272.946 us; speedup 1.0000x reference)
//
#include <hip/hip_runtime.h>

// Problem constants (from reference):
//   indices: int32 [16384, 200], values in [0, 100000)
//   W:       float32 [64, 100000]  (torch Linear weight layout: [dim, n_emb])
//   out:     float32 [16384, 200, 64] = table[indices], table = W.T
#define N_EMB 100000
#define DIM   64

// ---------------------------------------------------------------------------
// Kernel 1: transpose W [DIM][N_EMB] -> table [N_EMB][DIM] via LDS tile.
// Block = 256 threads, tile = 64 (n) x 64 (d). Both global read and write
// are coalesced; LDS padded to [64][65] -> conflict-free.
// ---------------------------------------------------------------------------
__global__ void transpose_w(const float* __restrict__ W,
                            float* __restrict__ table,
                            int n_emb) {
    __shared__ float tile[64][65];
    const int n0   = blockIdx.x * 64;
    const int t    = threadIdx.x;
    const int lane = t & 63;   // 0..63
    const int grp  = t >> 6;   // 0..3

    // Load: thread group `grp` covers d-rows [grp*16, grp*16+16); contiguous in n.
    #pragma unroll
    for (int i = 0; i < 16; ++i) {
        const int d = grp * 16 + i;
        const int n = n0 + lane;
        tile[d][lane] = (n < n_emb) ? W[(long long)d * N_EMB + n] : 0.0f;
    }
    __syncthreads();

    // Store: row n = n0 + grp*16 + i, contiguous in d across the 64 lanes.
    #pragma unroll
    for (int i = 0; i < 16; ++i) {
        const int n = n0 + grp * 16 + i;
        if (n < n_emb) table[(long long)n * DIM + lane] = tile[lane][grp * 16 + i];
    }
}

// ---------------------------------------------------------------------------
// Kernel 2: gather rows from table (contiguous 256 B rows) as float4.
// One float4 per lane per iteration; 16 consecutive lanes share one index
// (broadcast from cache), wave writes 1 KB fully coalesced.
// ---------------------------------------------------------------------------
__global__ void gather_f4(const int* __restrict__ idx,
                          const float4* __restrict__ table4,
                          float4* __restrict__ out4,
                          long long total_f4) {
    const long long stride = (long long)gridDim.x * blockDim.x;
    for (long long g = (long long)blockIdx.x * blockDim.x + threadIdx.x;
         g < total_f4; g += stride) {
        const long long row = g >> 4;        // which (b,h) row
        const int       e   = (int)(g & 15); // float4 slot within the 64-float row
        const int       id  = idx[row];
        out4[g] = table4[(long long)id * (DIM / 4) + e];
    }
}

// ---------------------------------------------------------------------------
// Fallback (ws too small): direct strided gather from W.
// ---------------------------------------------------------------------------
__global__ void gather_direct(const int* __restrict__ idx,
                              const float* __restrict__ W,
                              float* __restrict__ out,
                              long long total) {
    const long long stride = (long long)gridDim.x * blockDim.x;
    for (long long g = (long long)blockIdx.x * blockDim.x + threadIdx.x;
         g < total; g += stride) {
        const long long row = g >> 6;
        const int       d   = (int)(g & 63);
        out[g] = W[(long long)d * N_EMB + idx[row]];
    }
}

extern "C" void kernel_launch(void* const* d_in, const int* in_sizes, int n_in,
                              void* d_out, int out_size, void* d_ws, size_t ws_size,
                              hipStream_t stream) {
    const int*   idx = (const int*)d_in[0];    // [16384*200]
    const float* W   = (const float*)d_in[1];  // [64*100000]
    float*       out = (float*)d_out;          // [16384*200*64]

    const long long total    = (long long)out_size;       // 209,715,200 floats
    const size_t    tbl_bytes = (size_t)N_EMB * DIM * sizeof(float); // 25.6 MB

    if (ws_size >= tbl_bytes) {
        float* table = (float*)d_ws;

        // Transpose W -> table[N_EMB][DIM]
        const int tblocks = (N_EMB + 63) / 64; // 1563
        transpose_w<<<tblocks, 256, 0, stream>>>(W, table, N_EMB);

        // Gather as float4
        const long long total_f4 = total / 4;  // 52,428,800
        const int gblocks = 2048;              // 8 blocks/CU, grid-stride
        gather_f4<<<gblocks, 256, 0, stream>>>(idx, (const float4*)table,
                                               (float4*)out, total_f4);
    } else {
        const int gblocks = 2048;
        gather_direct<<<gblocks, 256, 0, stream>>>(idx, W, out, total);
    }
}